// Round 1
// 337.790 us; speedup vs baseline: 1.0250x; 1.0250x over previous
//
#include <hip/hip_runtime.h>

// Retrace loss: per-row backward affine recurrence y[s] = A[s]*y[s-1] + B[s],
// solved with a shuffle-based affine-map scan. One block per row.
//
// R1 change vs baseline: 256thr x 16elem -> 512thr x 8elem. Rationale: baseline
// compiled to 56 VGPRs, which CANNOT hold the intended 24-float4 prefetch
// (needs 96 regs) -> compiler serialized the loads into issue/wait batches ->
// latency-bound (VALUBusy 6.6%, HBM 20%, occupancy 34%). With EPT=8 the
// per-thread payload is 12 float4 = 48 VGPRs, which fits, and
// sched_barrier(0) pins all load issues before any consumption so the full
// set stays in flight. Serial per-thread chains also halve (8 steps vs 16).
// Memory-bound target: 6 x 64MiB fp32 reads, ~64us HBM floor (~50% L3-hit
// observed -> effective floor lower).

#define NROWS 4096
#define TLEN  4096
#define BLOCK 512
#define EPT   8
#define NWV   (BLOCK / 64)

__global__ __launch_bounds__(BLOCK) void retrace_main(
    const float* __restrict__ Q,
    const float* __restrict__ eQ,
    const float* __restrict__ tQ,
    const float* __restrict__ rw,
    const float* __restrict__ tpp,
    const float* __restrict__ bpp,
    double* __restrict__ partials)
{
    constexpr float G = 0.99f;
    __shared__ float sWA[NWV], sWB[NWV];
    __shared__ float sRed[NWV];

    const int tid  = threadIdx.x;
    const int lane = tid & 63;
    const int wv   = tid >> 6;
    const long long base = (long long)blockIdx.x * TLEN;
    // thread tid handles backward indices s in [EPT*tid, EPT*tid+EPT);
    // its element window starts at ua (covers t and u=t+1 needs).
    const int ua = (TLEN - EPT) - EPT * tid;   // 4088 - 8*tid

    // ---- Prefetch: issue ALL global loads (12 float4 + 4 boundary scalars),
    // in consumption order, then pin with sched_barrier so nothing sinks. ----
    float4 Tv4[2], Pv4[2], Qt4[2], Ev4[2], Rv4[2], Qm4[2];
    #pragma unroll
    for (int g = 0; g < 2; ++g) Tv4[g] = *(const float4*)(tpp + base + ua + 4 * g);
    #pragma unroll
    for (int g = 0; g < 2; ++g) Pv4[g] = *(const float4*)(bpp + base + ua + 4 * g);
    #pragma unroll
    for (int g = 0; g < 2; ++g) Qt4[g] = *(const float4*)(tQ  + base + ua + 4 * g);
    #pragma unroll
    for (int g = 0; g < 2; ++g) Ev4[g] = *(const float4*)(eQ  + base + ua + 4 * g);
    #pragma unroll
    for (int g = 0; g < 2; ++g) Rv4[g] = *(const float4*)(rw  + base + ua + 4 * g);

    // Wave-boundary threads (lane 0, tid != 0) can't shuffle from the previous
    // wave: load their shifted-window (index ua+EPT) scalars (L1/L2 hit).
    const bool bnd = (lane == 0) && (tid != 0);
    float bt = 0.f, bp = 0.f, bq = 0.f, be = 0.f;
    if (bnd) {
        bt = tpp[base + ua + EPT];
        bp = bpp[base + ua + EPT];
        bq = tQ [base + ua + EPT];
        be = eQ [base + ua + EPT];
    }

    // Q is consumed last (after the scan) -> issued last: its 2 loads stay in
    // flight across the entire scan phase.
    #pragma unroll
    for (int g = 0; g < 2; ++g) Qm4[g] = *(const float4*)(Q   + base + ua + 4 * g);

    __builtin_amdgcn_sched_barrier(0);   // do NOT sink any load issue below here

    // Flatten for indexed access (register arrays, fully unrolled use).
    float rv[EPT], tv[EPT], pv[EPT], qv[EPT], ev[EPT], qm[EPT];
    #pragma unroll
    for (int g = 0; g < 2; ++g) {
        rv[4*g+0]=Rv4[g].x; rv[4*g+1]=Rv4[g].y; rv[4*g+2]=Rv4[g].z; rv[4*g+3]=Rv4[g].w;
        tv[4*g+0]=Tv4[g].x; tv[4*g+1]=Tv4[g].y; tv[4*g+2]=Tv4[g].z; tv[4*g+3]=Tv4[g].w;
        pv[4*g+0]=Pv4[g].x; pv[4*g+1]=Pv4[g].y; pv[4*g+2]=Pv4[g].z; pv[4*g+3]=Pv4[g].w;
        qv[4*g+0]=Qt4[g].x; qv[4*g+1]=Qt4[g].y; qv[4*g+2]=Qt4[g].z; qv[4*g+3]=Qt4[g].w;
        ev[4*g+0]=Ev4[g].x; ev[4*g+1]=Ev4[g].y; ev[4*g+2]=Ev4[g].z; ev[4*g+3]=Ev4[g].w;
        qm[4*g+0]=Qm4[g].x; qm[4*g+1]=Qm4[g].y; qm[4*g+2]=Qm4[g].z; qm[4*g+3]=Qm4[g].w;
    }

    // ---- Build the EPT affine maps (index idx = m-1, m in [1,EPT]) ----
    // Map m: A = G*c[u], B = 100*r[u-1] + G*(eq[u] - c[u]*tq[u]), u = ua+m.
    float Aa[EPT], Bb[EPT];
    #pragma unroll
    for (int m = 1; m <= EPT - 1; ++m) {
        const float c  = __expf(fminf(tv[m] - pv[m], 0.0f));
        const float gc = G * c;
        const float f  = fmaf(-gc, qv[m], G * ev[m]);
        Aa[m-1] = gc;
        Bb[m-1] = fmaf(100.0f, rv[m-1], f);
    }
    // m = EPT: shifted-window element at ua+EPT == neighbor thread's m=0 element.
    {
        float t8 = __shfl_up(tv[0], 1, 64);
        float p8 = __shfl_up(pv[0], 1, 64);
        float q8 = __shfl_up(qv[0], 1, 64);
        float e8 = __shfl_up(ev[0], 1, 64);
        if (bnd) { t8 = bt; p8 = bp; q8 = bq; e8 = be; }
        if (tid == 0) {
            // s = 0: y = tQ[T-1] exactly (A = 0 kills any prior state).
            Aa[EPT-1] = 0.0f;
            Bb[EPT-1] = qv[EPT-1];     // tQ[base + 4095] is this thread's last element
        } else {
            const float c  = __expf(fminf(t8 - p8, 0.0f));
            const float gc = G * c;
            const float f  = fmaf(-gc, q8, G * e8);
            Aa[EPT-1] = gc;
            Bb[EPT-1] = fmaf(100.0f, rv[EPT-1], f);
        }
    }

    // ---- Local sequential composite (maps applied idx = EPT-1 down to 0) ----
    float Ac = 1.0f, Bc = 0.0f;
    #pragma unroll
    for (int k = 0; k < EPT; ++k) {
        const int idx = EPT - 1 - k;
        Bc = fmaf(Aa[idx], Bc, Bb[idx]);
        Ac = Aa[idx] * Ac;
    }

    // ---- Wave-level inclusive scan of affine maps (no barriers) ----
    float Ai = Ac, Bi = Bc;
    #pragma unroll
    for (int off = 1; off < 64; off <<= 1) {
        const float Ap = __shfl_up(Ai, off, 64);
        const float Bp = __shfl_up(Bi, off, 64);
        if (lane >= off) {
            Bi = fmaf(Ai, Bp, Bi);
            Ai = Ai * Ap;
        }
    }

    // ---- Cross-wave combine: NWV wave composites through LDS ----
    if (lane == 63) { sWA[wv] = Ai; sWB[wv] = Bi; }
    __syncthreads();
    // Incoming state for this wave = composite of waves 0..wv-1 applied to y0=0.
    // (That composite's A is exactly 0 for wv>=1 since thread 0 holds the s=0
    //  map with A=0 — only the B component survives.)
    float Bp = 0.0f;
    #pragma unroll
    for (int j = 0; j < NWV - 1; ++j)
        if (j < wv) Bp = fmaf(sWA[j], Bp, sWB[j]);

    // Exclusive-within-wave prefix, then compose with incoming wave state.
    float Ae = __shfl_up(Ai, 1, 64);
    float Be = __shfl_up(Bi, 1, 64);
    if (lane == 0) { Ae = 1.0f; Be = 0.0f; }
    float y = fmaf(Ae, Bp, Be);            // y entering this thread's chunk

    // ---- Apply maps locally + accumulate squared error vs Q ----
    float acc = 0.0f;
    #pragma unroll
    for (int k = 0; k < EPT; ++k) {
        const int idx = EPT - 1 - k;
        y = fmaf(Aa[idx], y, Bb[idx]);     // y = Q_ret[t], t = ua + idx
        const float d = qm[idx] - y;
        acc = fmaf(d, d, acc);
    }

    // ---- Block reduction: wave shuffle (width 64) + tiny LDS combine ----
    #pragma unroll
    for (int off = 32; off > 0; off >>= 1)
        acc += __shfl_down(acc, off, 64);
    if (lane == 0) sRed[wv] = acc;
    __syncthreads();
    if (tid == 0) {
        float s = 0.0f;
        #pragma unroll
        for (int j = 0; j < NWV; ++j) s += sRed[j];
        partials[blockIdx.x] = (double)s;  // every block writes its slot -> poison-safe
    }
}

#define FBLOCK 1024

__global__ __launch_bounds__(FBLOCK) void retrace_finalize(
    const double* __restrict__ partials, float* __restrict__ out)
{
    __shared__ double sRed[FBLOCK / 64];
    double s = 0.0;
    #pragma unroll
    for (int i = 0; i < NROWS / FBLOCK; ++i)
        s += partials[threadIdx.x + i * FBLOCK];
    #pragma unroll
    for (int off = 32; off > 0; off >>= 1)
        s += __shfl_down(s, off, 64);
    if ((threadIdx.x & 63) == 0) sRed[threadIdx.x >> 6] = s;
    __syncthreads();
    if (threadIdx.x == 0) {
        double tot = 0.0;
        #pragma unroll
        for (int j = 0; j < FBLOCK / 64; ++j) tot += sRed[j];
        out[0] = (float)(tot / ((double)NROWS * (double)TLEN));
    }
}

extern "C" void kernel_launch(void* const* d_in, const int* in_sizes, int n_in,
                              void* d_out, int out_size, void* d_ws, size_t ws_size,
                              hipStream_t stream)
{
    // setup_inputs order: Q, expected_target_Q, target_Q, rewards,
    //                     target_policy_probs, behaviour_policy_probs
    const float* Q   = (const float*)d_in[0];
    const float* eQ  = (const float*)d_in[1];
    const float* tQ  = (const float*)d_in[2];
    const float* rw  = (const float*)d_in[3];
    const float* tpp = (const float*)d_in[4];
    const float* bpp = (const float*)d_in[5];
    double* partials = (double*)d_ws;       // 4096 doubles = 32 KB scratch

    retrace_main<<<NROWS, BLOCK, 0, stream>>>(Q, eQ, tQ, rw, tpp, bpp, partials);
    retrace_finalize<<<1, FBLOCK, 0, stream>>>(partials, (float*)d_out);
}